// Round 2
// 325.724 us; speedup vs baseline: 1.0461x; 1.0461x over previous
//
#include <hip/hip_runtime.h>

// CubicSplineUpsampling: (2,3,96,96,96) f32 -> (2,3,192,192,192) f32.
//
// out_line(192) = M * in_line(96) per axis, M = U_clamped(192x96) . W(96x96),
// banded to 28 taps at j0=c-13 (truncation ~1e-8 relative).
//
// R(this): W is Toeplitz away from boundaries (corrections ~pole^c, pole=-0.268;
// <=~1e-4 abs for c>=12, tolerance 1.56e-2). So interior rows of M are ONE
// shifted 2x28 stencil == table rows 96/97. Hoist those 56 floats into
// SGPRs once per kernel -> interior inner loop is pure register FMA (no per-m
// s_load/waitcnt interlock, which missed scalar K$ at 21.5KB table).
// Chunks 8->12 so chunk edges align with interior split: boundary = c in
// [0,12) u [84,96) only (2 of 8 chunks). pass_z: 512 threads (8 waves x 12-c,
// single win[39], no shift) -> 16 waves/CU instead of 8.

#define TAPS 28
#define CHUNK 12
#define WIN (CHUNK + TAPS - 1)  // 39

__device__ double g_Wd[96 * 96];
__device__ float g_Mb[192 * TAPS];            // [i][t] row-major
__device__ float g_bufA[6 * 96 * 96 * 192];   // after Z pass
__device__ float g_bufB[6 * 96 * 192 * 192];  // after Y pass

__device__ __forceinline__ int clamp96(int j) { return j < 0 ? 0 : (j > 95 ? 95 : j); }

__global__ void compute_Wd_kernel(double* __restrict__ Wd) {
    int j = threadIdx.x;
    if (j >= 96) return;
    const double p = -0.26794919243112270647253365849413;  // sqrt(3)-2
    double c[96];
    double pj = 1.0;
    for (int t = 0; t < j; ++t) pj *= p;
    double p191j = 1.0;
    for (int t = 0; t < 191 - j; ++t) p191j *= p;
    double p2n = 1.0;
    for (int t = 0; t < 192; ++t) p2n *= p;
    double K = p / (1.0 - p2n);
    double cur = 6.0 * K * (pj + p191j) + (j == 0 ? 6.0 : 0.0);
    c[0] = cur;
    for (int i = 1; i < 96; ++i) {
        cur = (i == j ? 6.0 : 0.0) + p * cur;
        c[i] = cur;
    }
    double nxt = cur * (p / (p - 1.0));
    Wd[95 * 96 + j] = nxt;
    for (int i = 94; i >= 0; --i) {
        nxt = p * (nxt - c[i]);
        Wd[i * 96 + j] = nxt;
    }
}

__global__ void compute_M_kernel(const double* __restrict__ Wd, float* __restrict__ Mb) {
    int i = threadIdx.x;
    if (i >= 192) return;
    const double cw[8] = {1.0 / 384.0, 121.0 / 384.0, 235.0 / 384.0, 27.0 / 384.0,
                          27.0 / 384.0, 235.0 / 384.0, 121.0 / 384.0, 1.0 / 384.0};
    int ph = i & 1;
    int c = i >> 1;
    for (int t = 0; t < TAPS; ++t) {
        int j = c - 13 + t;
        double m = 0.0;
        if (j >= 0 && j < 96) {
            for (int tt = 0; tt < 4; ++tt) {
                int k = c + ph - 2 + tt;
                k = k < 0 ? 0 : (k > 95 ? 95 : k);
                m += cw[ph * 4 + tt] * Wd[k * 96 + j];
            }
        }
        Mb[i * TAPS + t] = (float)m;
    }
}

// Z pass: lines contiguous along z. Block: 64 lines staged in padded LDS.
// 512 threads: wave w (of 8) computes c in [12w, 12w+12) for all 64 lines
// (lane = line). Waves 1..6 are interior -> SGPR-stencil FMA only.
__global__ __launch_bounds__(512) void pass_z(const float* __restrict__ in,
                                              float* __restrict__ out,
                                              const float* __restrict__ Mb) {
    __shared__ float s_in[64 * 97];
    __shared__ float s_out[64 * 193];
    // Interior stencil (rows 96/97 = c=48, dead center): uniform loads -> SGPRs.
    float w0[TAPS], w1[TAPS];
#pragma unroll
    for (int t = 0; t < TAPS; ++t) {
        w0[t] = Mb[96 * TAPS + t];
        w1[t] = Mb[97 * TAPS + t];
    }
    size_t base = (size_t)blockIdx.x * 64;
    const float* src = in + base * 96;
    int tid = threadIdx.x;
    for (int k = tid; k < 64 * 96; k += 512)
        s_in[(k / 96) * 97 + (k % 96)] = src[k];
    __syncthreads();

    int lane = tid & 63;
    int wave = tid >> 6;
    int c0 = wave * CHUNK;
    const float* xl = s_in + lane * 97;
    float* op = s_out + lane * 193 + 2 * c0;
    float win[WIN];
#pragma unroll
    for (int k = 0; k < WIN; ++k) win[k] = xl[clamp96(c0 - 13 + k)];

    if (c0 >= 12 && c0 + CHUNK <= 84) {  // interior: pure register FMA
#pragma unroll
        for (int mi = 0; mi < CHUNK; ++mi) {
            float a0 = 0.f, a1 = 0.f;
#pragma unroll
            for (int t = 0; t < TAPS; ++t) {
                float xv = win[mi + t];
                a0 = fmaf(w0[t], xv, a0);
                a1 = fmaf(w1[t], xv, a1);
            }
            op[2 * mi] = a0;
            op[2 * mi + 1] = a1;
        }
    } else {  // boundary: per-m table rows
#pragma unroll
        for (int mi = 0; mi < CHUNK; ++mi) {
            int m = c0 + mi;
            int wb = __builtin_amdgcn_readfirstlane(m * 2 * TAPS);
            const float* wr = Mb + wb;
            float a0 = 0.f, a1 = 0.f;
#pragma unroll
            for (int t = 0; t < TAPS; ++t) {
                float xv = win[mi + t];
                a0 = fmaf(wr[t], xv, a0);
                a1 = fmaf(wr[TAPS + t], xv, a1);
            }
            op[2 * mi] = a0;
            op[2 * mi + 1] = a1;
        }
    }
    __syncthreads();
    float* dst = out + base * 192;
    for (int k = tid; k < 64 * 192; k += 512)
        dst[k] = s_out[(k / 192) * 193 + (k % 192)];
}

// Y/X pass: [O][96][INNER] -> [O][192][INNER]. Thread = (o, segment, r);
// consecutive lanes -> consecutive r (coalesced). Chunks of 12; interior
// chunks (mc in [12,84)) use the SGPR stencil, boundary chunks the table.
template <int INNER, int SEG>
__global__ __launch_bounds__(256) void pass_line(const float* __restrict__ in,
                                                 float* __restrict__ out,
                                                 const float* __restrict__ Mb) {
    constexpr int SPAN = 96 / SEG;
    constexpr int CHUNKS = SPAN / CHUNK;
    float w0[TAPS], w1[TAPS];
#pragma unroll
    for (int t = 0; t < TAPS; ++t) {
        w0[t] = Mb[96 * TAPS + t];
        w1[t] = Mb[97 * TAPS + t];
    }
    int idx = blockIdx.x * 256 + threadIdx.x;
    int r = idx % INNER;
    int q = idx / INNER;
    int s = q % SEG;
    int o = q / SEG;
    const float* src = in + (size_t)o * 96 * INNER + r;
    float* dst = out + (size_t)o * 192 * INNER + r;
    int m0 = s * SPAN;
    float win[WIN];
#pragma unroll
    for (int k = 0; k < WIN; ++k) win[k] = src[(size_t)clamp96(m0 - 13 + k) * INNER];
    for (int ch = 0; ch < CHUNKS; ++ch) {
        int mc = m0 + ch * CHUNK;
        float* d = dst + (size_t)(2 * mc) * INNER;
        if (mc >= 12 && mc + CHUNK <= 84) {  // interior
#pragma unroll
            for (int mi = 0; mi < CHUNK; ++mi) {
                float a0 = 0.f, a1 = 0.f;
#pragma unroll
                for (int t = 0; t < TAPS; ++t) {
                    float xv = win[mi + t];
                    a0 = fmaf(w0[t], xv, a0);
                    a1 = fmaf(w1[t], xv, a1);
                }
                d[0] = a0;
                d[(size_t)INNER] = a1;
                d += (size_t)2 * INNER;
            }
        } else {  // boundary
#pragma unroll
            for (int mi = 0; mi < CHUNK; ++mi) {
                int m = mc + mi;
                int wb = __builtin_amdgcn_readfirstlane(m * 2 * TAPS);
                const float* wr = Mb + wb;
                float a0 = 0.f, a1 = 0.f;
#pragma unroll
                for (int t = 0; t < TAPS; ++t) {
                    float xv = win[mi + t];
                    a0 = fmaf(wr[t], xv, a0);
                    a1 = fmaf(wr[TAPS + t], xv, a1);
                }
                d[0] = a0;
                d[(size_t)INNER] = a1;
                d += (size_t)2 * INNER;
            }
        }
        if (ch < CHUNKS - 1) {
#pragma unroll
            for (int k = 0; k < WIN - CHUNK; ++k) win[k] = win[k + CHUNK];
#pragma unroll
            for (int k = 0; k < CHUNK; ++k)
                win[WIN - CHUNK + k] = src[(size_t)clamp96(mc + (WIN - 13) + k) * INNER];
        }
    }
}

extern "C" void kernel_launch(void* const* d_in, const int* in_sizes, int n_in,
                              void* d_out, int out_size, void* d_ws, size_t ws_size,
                              hipStream_t stream) {
    const float* x = (const float*)d_in[0];
    float* out = (float*)d_out;
    double* Wd;
    float *Mb, *bufA, *bufB;
    hipGetSymbolAddress((void**)&Wd, HIP_SYMBOL(g_Wd));
    hipGetSymbolAddress((void**)&Mb, HIP_SYMBOL(g_Mb));
    hipGetSymbolAddress((void**)&bufA, HIP_SYMBOL(g_bufA));
    hipGetSymbolAddress((void**)&bufB, HIP_SYMBOL(g_bufB));

    compute_Wd_kernel<<<1, 96, 0, stream>>>(Wd);
    compute_M_kernel<<<1, 192, 0, stream>>>(Wd, Mb);

    // Z: 6*96*96 = 55296 lines / 64 per block, 512 threads (8 waves x 12-c)
    pass_z<<<864, 512, 0, stream>>>(x, bufA, Mb);
    // Y: O = 6*96 = 576, INNER = 192, SEG = 4 -> 576*4*192/256 = 1728 blocks
    pass_line<192, 4><<<1728, 256, 0, stream>>>(bufA, bufB, Mb);
    // X: O = 6, INNER = 192*192 = 36864, SEG = 2 -> 6*2*36864/256 = 1728 blocks
    pass_line<36864, 2><<<1728, 256, 0, stream>>>(bufB, out, Mb);
}